// Round 13
// baseline (478.163 us; speedup 1.0000x reference)
//
#include <hip/hip_runtime.h>

#define EPSF 1e-5f

typedef _Float16 h2f  __attribute__((ext_vector_type(2)));
typedef _Float16 h8   __attribute__((ext_vector_type(8)));
typedef float    f32x4 __attribute__((ext_vector_type(4)));

#if defined(__has_builtin)
#if __has_builtin(__builtin_amdgcn_fdot2)
#define HAVE_FDOT2 1
#endif
#endif

__device__ __forceinline__ float fsig(float x){ return 1.0f/(1.0f+__expf(-x)); }
__device__ __forceinline__ float ftanh(float x){
  float e = __expf(2.f*x);
  float r = (e-1.f)/(e+1.f);
  return (x > 15.f) ? 1.f : ((x < -15.f) ? -1.f : r);
}
__device__ __forceinline__ int pkf(float lo, float hi){
  return __builtin_bit_cast(int, __builtin_amdgcn_cvt_pkrtz(lo, hi));
}
__device__ __forceinline__ int4 mk4(const float* p){
  return make_int4(pkf(p[0],p[1]),pkf(p[2],p[3]),pkf(p[4],p[5]),pkf(p[6],p[7]));
}
__device__ __forceinline__ float dot2(int w, int x, float acc){
#ifdef HAVE_FDOT2
  return __builtin_amdgcn_fdot2(__builtin_bit_cast(h2f, w),
                                __builtin_bit_cast(h2f, x), acc, false);
#else
  h2f a = __builtin_bit_cast(h2f, w), b = __builtin_bit_cast(h2f, x);
  return acc + (float)a[0]*(float)b[0] + (float)a[1]*(float)b[1];
#endif
}
__device__ __forceinline__ int rl_i(int v, int l){ return __builtin_amdgcn_readlane(v, l); }
__device__ __forceinline__ float rl_f(float v, int l){
  return __int_as_float(__builtin_amdgcn_readlane(__float_as_int(v), l));
}
// light barrier: order LDS only; global loads/stores stay in flight
#define BAR() do{ asm volatile("s_waitcnt lgkmcnt(0)" ::: "memory"); __builtin_amdgcn_s_barrier(); }while(0)

// ---------------------------------------------------------------------------
// Kernel 1: msum[t] = sum_{b,n} masks[b,t,n] + EPS   (one block per t)
// ---------------------------------------------------------------------------
__global__ void msum_kernel(const float* __restrict__ masks, float* __restrict__ msum){
  const int t   = blockIdx.x;
  const int tid = threadIdx.x;
  const int b0  = tid >> 3;
  const int n4  = (tid & 7) << 2;
  float s = 0.f;
  #pragma unroll 4
  for (int i = 0; i < 32; ++i) {
    const int b = b0 + (i << 5);
    const float4 v = *reinterpret_cast<const float4*>(masks + ((size_t)b*256 + t)*32 + n4);
    s += v.x + v.y + v.z + v.w;
  }
  __shared__ float red[256];
  red[tid] = s; __syncthreads();
  for (int off = 128; off > 0; off >>= 1) {
    if (tid < off) red[tid] += red[tid + off];
    __syncthreads();
  }
  if (tid == 0) msum[t] = red[0] + EPSF;
}

// ---------------------------------------------------------------------------
// Kernel 2: persistent RNN. 256 blocks x 512 threads, 4 batch elems / block.
// r11/r12 structure; register-budget fix: fC (hist) + wz (feat) stay
// VGPR-resident (critical middle of the chain), fB (td_h) + fDa (wc) served
// from conflict-free group-major LDS (early/late matvecs, latency-hidden).
// Live-across-loop ~115 regs -> fits the 128 cap with NO spill (r11/r12
// spilled ~35 regs -> 9.7MB scratch writes on the chain critical path).
// ---------------------------------------------------------------------------
__global__ __launch_bounds__(512, 1) void rits_kernel(
  const float* __restrict__ values, const float* __restrict__ masks,
  const float* __restrict__ deltas, const float* __restrict__ labels,
  const float* __restrict__ is_train,
  const float* __restrict__ td_h_W, const float* __restrict__ td_h_b,
  const float* __restrict__ td_x_W, const float* __restrict__ td_x_b,
  const float* __restrict__ hist_W, const float* __restrict__ hist_b,
  const float* __restrict__ feat_W, const float* __restrict__ feat_b,
  const float* __restrict__ wc_W,  const float* __restrict__ wc_b,
  const float* __restrict__ W_ih,  const float* __restrict__ W_hh,
  const float* __restrict__ b_ih,  const float* __restrict__ b_hh,
  const float* __restrict__ out_W, const float* __restrict__ out_b,
  const float* __restrict__ msum,
  float* __restrict__ xl_acc, float* __restrict__ bce_acc,
  float* __restrict__ predictions, float* __restrict__ imps)
{
  // group-major packed weights: [group][lane] int4 = 4 packed pairs,
  // 16B/lane contiguous -> conflict-free ds_read_b128.
  __shared__ __align__(16) int4 pkB[4][64];    // td_h_W row j, K=32
  __shared__ __align__(16) int4 pkDa[8][32];   // wc_W row n, K=64 ([gx|m])
  // [e][ ccw 0..15 | mw 16..31 | hw 32..63 ] ; stride 84 (84%32=20) ->
  // rows 0..3 land on distinct banks for same-word reads.
  __shared__ __align__(16) int  inp_s[4][84];
  __shared__ float gp[4][256];    // [elem][gate row]
  __shared__ float msum_l[256];   // 1/msum[t]

  const int tid = threadIdx.x;
  const int b   = blockIdx.x;
  const int wv  = tid >> 6;          // 0..7
  const int ln  = tid & 63;
  const bool chain = (wv < 4);
  const int me  = wv & 3;
  const int b2  = (b << 2) | me;

  if (tid < 256) msum_l[tid] = 1.0f / msum[tid];
  // stage pkB / pkDa (first 256 threads)
  if (tid < 256){ const int g = tid >> 6, j = tid & 63;
    const float* w = td_h_W + j*32 + 8*g;
    pkB[g][j] = make_int4(pkf(w[0],w[1]), pkf(w[2],w[3]), pkf(w[4],w[5]), pkf(w[6],w[7])); }
  if (tid < 256){ const int g = tid >> 5, n = tid & 31;
    const float* w = wc_W + n*64 + 8*g;
    pkDa[g][n] = make_int4(pkf(w[0],w[1]), pkf(w[2],w[3]), pkf(w[4],w[5]), pkf(w[6],w[7])); }

  // ---- per-thread gate B-fragments (all 8 waves): 2 n-tiles x 4 k-steps ----
  int4 Wb[2][4];
  const int kg = ln >> 4;
  #pragma unroll
  for (int nt = 0; nt < 2; ++nt){
    const int col = (wv << 5) + (nt << 4) + (ln & 15);
    #pragma unroll
    for (int ks = 0; ks < 4; ++ks){
      const int k0 = (ks << 5) + (kg << 3);
      const float* src = (k0 < 64) ? (W_ih + (size_t)col*64 + k0)
                                   : (W_hh + (size_t)col*64 + (k0 - 64));
      Wb[nt][ks] = make_int4(pkf(src[0],src[1]), pkf(src[2],src[3]),
                             pkf(src[4],src[5]), pkf(src[6],src[7]));
    }
  }
  const int col0 = (wv << 5) + (ln & 15);
  const float bs0 = b_ih[col0]      + b_hh[col0];
  const float bs1 = b_ih[col0 + 16] + b_hh[col0 + 16];

  // ---- chain-wave VGPR weights (critical middle only) + registers ----
  int4  fC[8];      // hist_W row (ln&31) (K=64)
  float wz[32];     // feat_W row (ln&31), fp32, diag 0
  float thb_r=0.f, tdxd_r=0.f, tdxb_r=0.f, histb_r=0.f, featb_r=0.f, wcb_r=0.f;
  float xv=0.f, mv=0.f, dv=0.f;
  if (chain){
    const int nr = ln & 31;
    #pragma unroll
    for (int g = 0; g < 8; ++g) fC[g] = mk4(hist_W + nr*64 + 8*g);
    #pragma unroll
    for (int k = 0; k < 32; ++k) wz[k] = (k==nr) ? 0.f : feat_W[nr*32 + k];
    thb_r = td_h_b[ln];
    if (ln < 32){
      tdxd_r  = td_x_W[ln*33];
      tdxb_r  = td_x_b[ln];
      histb_r = hist_b[ln];
      featb_r = feat_b[ln];
      wcb_r   = wc_b[ln];
      const size_t base = (size_t)b2*8192 + ln;
      xv = values[base]; mv = masks[base]; dv = deltas[base];
    }
  }
  float h_reg = 0.f, c_reg = 0.f, loss_acc = 0.f;

  __syncthreads();

  for (int t = 0; t < 256; ++t){
    // ---- chain A-D ----
    if (chain){
      const float x_cur = xv, m_cur = mv, d_cur = dv;
      float gx_r = 0.f;
      if (ln < 32){
        gx_r = __expf(-fmaxf(fmaf(d_cur, tdxd_r, tdxb_r), 0.f));
        if (t < 255){
          const size_t base = (size_t)b2*8192 + (size_t)(t+1)*32 + ln;
          xv = values[base]; mv = masks[base]; dv = deltas[base];
        }
      }
      const int i0 = (2*ln) & 63, i1 = (2*ln+1) & 63;
      const int dw = pkf(__shfl(d_cur, i0), __shfl(d_cur, i1));   // words 0..15 valid
      // aw pack hoisted here (inputs ready; off the serial B->C->D path)
      const int j0 = (2*ln-32) & 63, j1 = (2*ln-31) & 63;
      const float ga  = __shfl(gx_r,  i0), gb  = __shfl(gx_r,  i1);
      const float ma_ = __shfl(m_cur, j0), mb_ = __shfl(m_cur, j1);
      const int aw = (ln < 16) ? pkf(ga, gb) : pkf(ma_, mb_);     // gx|m pairs

      // B: gamma_h (64 rows, K=32, LDS weights -- reads overlap the dw pack)
      {
        float a0 = thb_r, a1 = 0.f;
        #pragma unroll
        for (int g4 = 0; g4 < 4; ++g4){
          const int4 w = pkB[g4][ln];
          a0 = dot2(w.x, rl_i(dw, 4*g4+0), a0);
          a1 = dot2(w.y, rl_i(dw, 4*g4+1), a1);
          a0 = dot2(w.z, rl_i(dw, 4*g4+2), a0);
          a1 = dot2(w.w, rl_i(dw, 4*g4+3), a1);
        }
        h_reg *= __expf(-fmaxf(a0+a1, 0.f));
      }
      const int hw = pkf(__shfl(h_reg, i0), __shfl(h_reg, i1));   // h pairs
      // C: x_h (32 rows, K=64, VGPR weights); x_c
      float xh_v = 0.f, x_c_v = 0.f;
      if (ln < 32){
        float a0 = histb_r, a1 = 0.f, a2 = 0.f, a3 = 0.f;
        #pragma unroll
        for (int g4 = 0; g4 < 8; ++g4){
          const int4 w = fC[g4];
          a0 = dot2(w.x, rl_i(hw, 4*g4+0), a0);
          a1 = dot2(w.y, rl_i(hw, 4*g4+1), a1);
          a2 = dot2(w.z, rl_i(hw, 4*g4+2), a2);
          a3 = dot2(w.w, rl_i(hw, 4*g4+3), a3);
        }
        xh_v  = (a0+a1)+(a2+a3);
        x_c_v = m_cur*x_cur + (1.f-m_cur)*xh_v;
      }
      // D: z (fp32 readlane of x_c -- no pack), alpha (LDS weights), c_h,
      //    loss, imputation
      float ccv = 0.f;
      if (ln < 32){
        float z0 = featb_r, z1 = 0.f, z2 = 0.f, z3 = 0.f;
        #pragma unroll
        for (int k = 0; k < 32; k += 4){
          z0 = fmaf(rl_f(x_c_v, k+0), wz[k+0], z0);
          z1 = fmaf(rl_f(x_c_v, k+1), wz[k+1], z1);
          z2 = fmaf(rl_f(x_c_v, k+2), wz[k+2], z2);
          z3 = fmaf(rl_f(x_c_v, k+3), wz[k+3], z3);
        }
        const float z = (z0+z1)+(z2+z3);
        float a0 = wcb_r, a1 = 0.f, a2 = 0.f, a3 = 0.f;
        #pragma unroll
        for (int g4 = 0; g4 < 8; ++g4){
          const int4 w = pkDa[g4][ln];
          a0 = dot2(w.x, rl_i(aw, 4*g4+0), a0);
          a1 = dot2(w.y, rl_i(aw, 4*g4+1), a1);
          a2 = dot2(w.z, rl_i(aw, 4*g4+2), a2);
          a3 = dot2(w.w, rl_i(aw, 4*g4+3), a3);
        }
        const float al = (a0+a1)+(a2+a3);
        const float ch = al*z + (1.f-al)*xh_v;
        loss_acc += (fabsf(x_cur-xh_v)+fabsf(x_cur-z)+fabsf(x_cur-ch))*m_cur*msum_l[t];
        ccv = m_cur*x_cur + (1.f-m_cur)*ch;
        imps[(size_t)b2*8192 + (size_t)t*32 + ln] = ccv;
      }
      const int ccw = pkf(__shfl(ccv, i0), __shfl(ccv, i1));      // words 0..15
      inp_s[me][ln] = (ln < 16) ? ccw : (ln < 32 ? aw : hw);
    }

    BAR();   // inp_s visible to all waves

    // ---- E: gate GEMM via MFMA; A rows = elems 0..3, rows 4..15 zero ----
    {
      const int arow = ln & 15;
      int4 A[4];
      if (arow < 4){
        #pragma unroll
        for (int ks = 0; ks < 4; ++ks)
          A[ks] = *reinterpret_cast<const int4*>(&inp_s[arow][(ks << 4) + (kg << 2)]);
      } else {
        #pragma unroll
        for (int ks = 0; ks < 4; ++ks) A[ks] = make_int4(0,0,0,0);
      }
      f32x4 acc0 = {bs0, bs0, bs0, bs0};
      f32x4 acc1 = {bs1, bs1, bs1, bs1};
      #pragma unroll
      for (int ks = 0; ks < 4; ++ks){
        acc0 = __builtin_amdgcn_mfma_f32_16x16x32_f16(
                 __builtin_bit_cast(h8, A[ks]), __builtin_bit_cast(h8, Wb[0][ks]), acc0, 0,0,0);
        acc1 = __builtin_amdgcn_mfma_f32_16x16x32_f16(
                 __builtin_bit_cast(h8, A[ks]), __builtin_bit_cast(h8, Wb[1][ks]), acc1, 0,0,0);
      }
      // C/D: col=lane&15, row=(lane>>4)*4+reg -> kg==0 lanes hold rows 0-3
      if (kg == 0){
        #pragma unroll
        for (int e = 0; e < 4; ++e){
          gp[e][col0]      = acc0[e];
          gp[e][col0 + 16] = acc1[e];
        }
      }
    }

    BAR();   // gates visible to chain waves

    // ---- F: LSTM pointwise update (chain waves) ----
    if (chain){
      const float ig = gp[me][ln];
      const float fg = gp[me][64+ln];
      const float gg = gp[me][128+ln];
      const float og = gp[me][192+ln];
      c_reg = fsig(fg)*c_reg + fsig(ig)*ftanh(gg);
      h_reg = fsig(og)*ftanh(c_reg);
    }
  }

  // ---- epilogue: loss reduce + prediction/BCE (chain waves) ----
  if (chain){
    float l = loss_acc;   // nonzero only on ln<32
    l += __shfl_xor(l,16); l += __shfl_xor(l,8);
    l += __shfl_xor(l,4);  l += __shfl_xor(l,2); l += __shfl_xor(l,1);
    if (ln == 0) atomicAdd(xl_acc, l);

    float p = h_reg * out_W[ln];
    p += __shfl_xor(p,32); p += __shfl_xor(p,16); p += __shfl_xor(p,8);
    p += __shfl_xor(p,4);  p += __shfl_xor(p,2);  p += __shfl_xor(p,1);
    if (ln == 0){
      const float y = p + out_b[0];
      predictions[b2] = fsig(y);
      const float lab = labels[b2];
      const float it  = is_train[b2];
      const float mx  = fmaxf(-y, 0.f);
      const float bce = y - y*lab + mx + __logf(__expf(-mx) + __expf(-y - mx));
      atomicAdd(bce_acc, bce * it);
    }
  }
}

// ---------------------------------------------------------------------------
// Kernel 3: finalize loss scalar
// ---------------------------------------------------------------------------
__global__ void final_kernel(const float* __restrict__ is_train,
                             const float* __restrict__ ws,
                             float* __restrict__ out){
  const int tid = threadIdx.x;
  __shared__ float red[256];
  red[tid] = is_train[tid] + is_train[tid+256] + is_train[tid+512] + is_train[tid+768];
  __syncthreads();
  for (int off = 128; off > 0; off >>= 1){
    if (tid < off) red[tid] += red[tid + off];
    __syncthreads();
  }
  if (tid == 0){
    const float yl = ws[1] / (red[0] + EPSF);
    out[0] = ws[0] / 256.0f + 0.1f * yl;
  }
}

extern "C" void kernel_launch(void* const* d_in, const int* in_sizes, int n_in,
                              void* d_out, int out_size, void* d_ws, size_t ws_size,
                              hipStream_t stream){
  const float* values   = (const float*)d_in[0];
  const float* masks    = (const float*)d_in[1];
  const float* deltas   = (const float*)d_in[2];
  const float* labels   = (const float*)d_in[5];
  const float* is_train = (const float*)d_in[6];
  const float* td_h_W   = (const float*)d_in[7];
  const float* td_h_b   = (const float*)d_in[8];
  const float* td_x_W   = (const float*)d_in[9];
  const float* td_x_b   = (const float*)d_in[10];
  const float* hist_W   = (const float*)d_in[11];
  const float* hist_b   = (const float*)d_in[12];
  const float* feat_W   = (const float*)d_in[13];
  const float* feat_b   = (const float*)d_in[14];
  const float* wc_W     = (const float*)d_in[15];
  const float* wc_b     = (const float*)d_in[16];
  const float* W_ih     = (const float*)d_in[17];
  const float* W_hh     = (const float*)d_in[18];
  const float* b_ih     = (const float*)d_in[19];
  const float* b_hh     = (const float*)d_in[20];
  const float* out_W    = (const float*)d_in[21];
  const float* out_b    = (const float*)d_in[22];

  float* out = (float*)d_out;                 // [0]=loss, [1..1025)=preds, [1025..)=imps
  float* ws  = (float*)d_ws;                  // [0]=xl_sum, [1]=bce_sum, [2..258)=msum

  hipMemsetAsync(ws, 0, 2*sizeof(float), stream);
  msum_kernel<<<256, 256, 0, stream>>>(masks, ws + 2);
  rits_kernel<<<256, 512, 0, stream>>>(values, masks, deltas, labels, is_train,
      td_h_W, td_h_b, td_x_W, td_x_b, hist_W, hist_b, feat_W, feat_b,
      wc_W, wc_b, W_ih, W_hh, b_ih, b_hh, out_W, out_b,
      ws + 2, ws + 0, ws + 1, out + 1, out + 1 + 1024);
  final_kernel<<<1, 256, 0, stream>>>(is_train, ws, out);
}